// Round 2
// baseline (1541.140 us; speedup 1.0000x reference)
//
#include <hip/hip_runtime.h>
#include <hip/hip_bf16.h>
#include <math.h>

#define IN_CH  256
#define MID    512
#define MID2   256
#define OUT_CH 64

// ---------------- CSR build ----------------

__global__ __launch_bounds__(256) void deg_kernel(const int* __restrict__ dst,
                                                  int* __restrict__ cnt, int E) {
  int stride = gridDim.x * blockDim.x;
  for (int e = blockIdx.x * blockDim.x + threadIdx.x; e < E; e += stride)
    atomicAdd(&cnt[dst[e]], 1);
}

// single block, 1024 threads: rowstart = exclusive scan of (deg+1); dis = rsqrt(deg+1)
__global__ __launch_bounds__(1024) void scan_dis_kernel(const int* __restrict__ cnt,
                                                        int* __restrict__ rowstart,
                                                        float* __restrict__ dis, int N) {
  __shared__ int part[1024];
  int t = threadIdx.x;
  int chunk = (N + 1023) >> 10;
  int lo = t * chunk;
  int hi = lo + chunk; if (hi > N) hi = N; if (lo > N) lo = N;
  int s = 0;
  for (int i = lo; i < hi; ++i) s += cnt[i] + 1;
  part[t] = s;
  __syncthreads();
  for (int off = 1; off < 1024; off <<= 1) {
    int v = (t >= off) ? part[t - off] : 0;
    __syncthreads();
    part[t] += v;
    __syncthreads();
  }
  int base = part[t] - s;  // exclusive prefix
  for (int i = lo; i < hi; ++i) {
    int d = cnt[i] + 1;
    rowstart[i] = base;
    dis[i] = rsqrtf((float)d);
    base += d;
  }
  if (t == 1023) rowstart[N] = part[1023];
}

__global__ __launch_bounds__(256) void fill_adj_kernel(const int* __restrict__ src,
                                                       const int* __restrict__ dst,
                                                       const int* __restrict__ rowstart,
                                                       int* __restrict__ cnt2,
                                                       int* __restrict__ adj,
                                                       int E, int N) {
  int total = E + N;
  int stride = gridDim.x * blockDim.x;
  for (int e = blockIdx.x * blockDim.x + threadIdx.x; e < total; e += stride) {
    int s, d;
    if (e < E) { s = src[e]; d = dst[e]; }
    else       { s = d = e - E; }                 // self-loop
    int pos = rowstart[d] + atomicAdd(&cnt2[d], 1);
    adj[pos] = s;
  }
}

// ---------------- fp32 GEMM 128x128 tile, 8x8 micro (split-half mapping) ----------
// C[N x Fout] = A[N x K] @ W[K x Fout] (+bias).  Fout % 128 == 0, K % 16 == 0.
// Micro-tile rows: ty*4+i and 64+ty*4+i; cols: tx*4+j and 64+tx*4+j.
// -> B-tile LDS reads are 16B slots spanning 256B = 2-way (free); A-tile reads
//    are 4 broadcast addresses = conflict-free. 1 B LDS per FMA = balanced.

template<bool ADD_BIAS>
__global__ __launch_bounds__(256, 2) void gemm128(const float* __restrict__ A,
                                                  const float* __restrict__ W,
                                                  const float* __restrict__ bias,
                                                  float* __restrict__ C,
                                                  int Nrows, int K, int Fout) {
  __shared__ float As[16][128];   // As[k][m] (transposed)
  __shared__ float Bs[16][128];   // Bs[k][n]
  const int tid  = threadIdx.x;
  const int row0 = blockIdx.x * 128;
  const int col0 = blockIdx.y * 128;
  const int tx   = tid & 15;         // col group
  const int ty   = tid >> 4;         // row group (0..15)
  const int la_r = tid >> 1;         // A-tile row 0..127
  const int la_c = (tid & 1) << 3;   // A-tile col 0 or 8
  const int lb_r = tid >> 4;         // B-tile k-row 0..15
  const int lb_c = (tid & 15) << 3;  // B-tile col 0,8,..,120

  float acc[8][8];
  #pragma unroll
  for (int i = 0; i < 8; ++i)
    #pragma unroll
    for (int j = 0; j < 8; ++j) acc[i][j] = 0.f;

  for (int k0 = 0; k0 < K; k0 += 16) {
    float4 a0 = make_float4(0.f, 0.f, 0.f, 0.f), a1 = a0;
    int ar = row0 + la_r;
    if (ar < Nrows) {
      const float* ap = A + (size_t)ar * K + (k0 + la_c);
      a0 = *(const float4*)ap;
      a1 = *(const float4*)(ap + 4);
    }
    const float* wp = W + (size_t)(k0 + lb_r) * Fout + (col0 + lb_c);
    float4 b0 = *(const float4*)wp;
    float4 b1 = *(const float4*)(wp + 4);
    __syncthreads();  // previous iteration's reads done before overwrite
    As[la_c + 0][la_r] = a0.x;
    As[la_c + 1][la_r] = a0.y;
    As[la_c + 2][la_r] = a0.z;
    As[la_c + 3][la_r] = a0.w;
    As[la_c + 4][la_r] = a1.x;
    As[la_c + 5][la_r] = a1.y;
    As[la_c + 6][la_r] = a1.z;
    As[la_c + 7][la_r] = a1.w;
    *(float4*)&Bs[lb_r][lb_c]     = b0;
    *(float4*)&Bs[lb_r][lb_c + 4] = b1;
    __syncthreads();
    #pragma unroll
    for (int k = 0; k < 16; ++k) {
      float4 A0 = *(const float4*)&As[k][ty << 2];
      float4 A1 = *(const float4*)&As[k][64 + (ty << 2)];
      float4 B0 = *(const float4*)&Bs[k][tx << 2];
      float4 B1 = *(const float4*)&Bs[k][64 + (tx << 2)];
      float a[8] = {A0.x, A0.y, A0.z, A0.w, A1.x, A1.y, A1.z, A1.w};
      float b[8] = {B0.x, B0.y, B0.z, B0.w, B1.x, B1.y, B1.z, B1.w};
      #pragma unroll
      for (int i = 0; i < 8; ++i)
        #pragma unroll
        for (int j = 0; j < 8; ++j) acc[i][j] = fmaf(a[i], b[j], acc[i][j]);
    }
  }

  #pragma unroll
  for (int ih = 0; ih < 2; ++ih) {
    #pragma unroll
    for (int i = 0; i < 4; ++i) {
      int r = row0 + ih * 64 + (ty << 2) + i;
      if (r >= Nrows) continue;
      #pragma unroll
      for (int jh = 0; jh < 2; ++jh) {
        int c = col0 + jh * 64 + (tx << 2);
        float4 v = make_float4(acc[ih * 4 + i][jh * 4 + 0],
                               acc[ih * 4 + i][jh * 4 + 1],
                               acc[ih * 4 + i][jh * 4 + 2],
                               acc[ih * 4 + i][jh * 4 + 3]);
        if (ADD_BIAS) {
          const float* bp = bias + c;
          v.x += bp[0]; v.y += bp[1]; v.z += bp[2]; v.w += bp[3];
        }
        *(float4*)(C + (size_t)r * Fout + c) = v;
      }
    }
  }
}

// ---------------- fp32 GEMM 64x64 (for Fout=64 layer) ----------------

template<bool ADD_BIAS>
__global__ __launch_bounds__(256) void gemm64(const float* __restrict__ A,
                                              const float* __restrict__ W,
                                              const float* __restrict__ bias,
                                              float* __restrict__ C,
                                              int Nrows, int K, int Fout) {
  __shared__ float As[16][64];   // As[k][m]
  __shared__ float Bs[16][64];   // Bs[k][n]
  const int tid  = threadIdx.x;
  const int row0 = blockIdx.x * 64;
  const int col0 = blockIdx.y * 64;
  const int tx   = tid & 15;
  const int ty   = tid >> 4;
  const int la_r = tid >> 2;
  const int la_c = (tid & 3) << 2;
  const int lb_r = tid >> 4;
  const int lb_c = (tid & 15) << 2;

  float acc[4][4];
  #pragma unroll
  for (int i = 0; i < 4; ++i)
    #pragma unroll
    for (int j = 0; j < 4; ++j) acc[i][j] = 0.f;

  for (int k0 = 0; k0 < K; k0 += 16) {
    float4 av = make_float4(0.f, 0.f, 0.f, 0.f);
    int ar = row0 + la_r;
    if (ar < Nrows) av = *(const float4*)(A + (size_t)ar * K + (k0 + la_c));
    float4 bv = *(const float4*)(W + (size_t)(k0 + lb_r) * Fout + (col0 + lb_c));
    __syncthreads();
    As[la_c + 0][la_r] = av.x;
    As[la_c + 1][la_r] = av.y;
    As[la_c + 2][la_r] = av.z;
    As[la_c + 3][la_r] = av.w;
    *(float4*)&Bs[lb_r][lb_c] = bv;
    __syncthreads();
    #pragma unroll
    for (int k = 0; k < 16; ++k) {
      float4 a4 = *(const float4*)&As[k][ty << 2];
      float4 b4 = *(const float4*)&Bs[k][tx << 2];
      float a[4] = {a4.x, a4.y, a4.z, a4.w};
      float b[4] = {b4.x, b4.y, b4.z, b4.w};
      #pragma unroll
      for (int i = 0; i < 4; ++i)
        #pragma unroll
        for (int j = 0; j < 4; ++j) acc[i][j] = fmaf(a[i], b[j], acc[i][j]);
    }
  }

  #pragma unroll
  for (int i = 0; i < 4; ++i) {
    int r = row0 + (ty << 2) + i;
    if (r < Nrows) {
      float4 v = make_float4(acc[i][0], acc[i][1], acc[i][2], acc[i][3]);
      if (ADD_BIAS) {
        const float* bp = bias + col0 + (tx << 2);
        v.x += bp[0]; v.y += bp[1]; v.z += bp[2]; v.w += bp[3];
      }
      *(float4*)(C + (size_t)r * Fout + col0 + (tx << 2)) = v;
    }
  }
}

// ---------------- aggregation: one wave per node ----------------
// out[i] += epilogue( dis[i] * sum_{s in adj(i)} H[s]*dis[s] + bias )

template<int F, bool DO_ELU>
__global__ __launch_bounds__(256) void agg_kernel(const float* __restrict__ H,
                                                  const int* __restrict__ adj,
                                                  const int* __restrict__ rowstart,
                                                  const float* __restrict__ dis,
                                                  const float* __restrict__ bias,
                                                  float* __restrict__ out, int N) {
  constexpr int VF = F / 64;  // floats per lane
  int gid  = blockIdx.x * blockDim.x + threadIdx.x;
  int node = gid >> 6;
  int lane = threadIdx.x & 63;
  if (node >= N) return;

  float acc[VF];
  #pragma unroll
  for (int j = 0; j < VF; ++j) acc[j] = 0.f;

  int e = rowstart[node], end = rowstart[node + 1];
  for (; e < end; ++e) {
    int s = adj[e];
    float w = dis[s];
    const float* hp = H + (size_t)s * F + lane * VF;
    #pragma unroll
    for (int j = 0; j < VF; ++j) acc[j] = fmaf(hp[j], w, acc[j]);
  }

  float di = dis[node];
  const float* bp = bias + lane * VF;
  float* op = out + (size_t)node * F + lane * VF;
  #pragma unroll
  for (int j = 0; j < VF; ++j) {
    float v = fmaf(acc[j], di, bp[j]);
    if (DO_ELU) v = (v > 0.f) ? v : expm1f(v);
    op[j] += v;
  }
}

// ---------------- launch ----------------

extern "C" void kernel_launch(void* const* d_in, const int* in_sizes, int n_in,
                              void* d_out, int out_size, void* d_ws, size_t ws_size,
                              hipStream_t stream) {
  const float* x   = (const float*)d_in[0];
  const int*  eidx = (const int*)d_in[1];
  const float* Wg1 = (const float*)d_in[2];
  const float* bg1 = (const float*)d_in[3];
  const float* Wg2 = (const float*)d_in[4];
  const float* bg2 = (const float*)d_in[5];
  const float* Wg3 = (const float*)d_in[6];
  const float* bg3 = (const float*)d_in[7];
  const float* Wl1 = (const float*)d_in[8];
  const float* bl1 = (const float*)d_in[9];
  const float* Wl2 = (const float*)d_in[10];
  const float* bl2 = (const float*)d_in[11];
  const float* Wl3 = (const float*)d_in[12];
  const float* bl3 = (const float*)d_in[13];

  const int N = in_sizes[0] / IN_CH;
  const int E = in_sizes[1] / 2;
  const int* esrc = eidx;
  const int* edst = eidx + E;

  char* ws = (char*)d_ws;
  float* h1       = (float*)ws; ws += (size_t)N * MID  * 4;
  float* h2       = (float*)ws; ws += (size_t)N * MID2 * 4;
  float* Hb       = (float*)ws; ws += (size_t)N * MID  * 4;   // GCN-branch scratch
  float* dis      = (float*)ws; ws += (size_t)N * 4;
  int*   rowstart = (int*)ws;   ws += (size_t)(N + 1) * 4;
  int*   cnt      = (int*)ws;   ws += (size_t)N * 4;
  int*   cnt2     = (int*)ws;   ws += (size_t)N * 4;          // contiguous with cnt
  int*   adj      = (int*)ws;   ws += (size_t)(E + N) * 4;

  hipMemsetAsync(cnt, 0, (size_t)2 * N * 4, stream);  // cnt + cnt2
  deg_kernel<<<1024, 256, 0, stream>>>(edst, cnt, E);
  scan_dis_kernel<<<1, 1024, 0, stream>>>(cnt, rowstart, dis, N);
  fill_adj_kernel<<<2048, 256, 0, stream>>>(esrc, edst, rowstart, cnt2, adj, E, N);

  int aggBlocks = (N + 3) / 4;  // 4 waves (=4 nodes) per 256-thread block

  // layer 1: h1 = elu(agg(x@Wg1)+bg1) + x@Wl1 + bl1
  dim3 g1((N + 127) / 128, MID / 128);
  gemm128<true ><<<g1, 256, 0, stream>>>(x, Wl1, bl1, h1, N, IN_CH, MID);
  gemm128<false><<<g1, 256, 0, stream>>>(x, Wg1, nullptr, Hb, N, IN_CH, MID);
  agg_kernel<MID, true><<<aggBlocks, 256, 0, stream>>>(Hb, adj, rowstart, dis, bg1, h1, N);

  // layer 2
  dim3 g2((N + 127) / 128, MID2 / 128);
  gemm128<true ><<<g2, 256, 0, stream>>>(h1, Wl2, bl2, h2, N, MID, MID2);
  gemm128<false><<<g2, 256, 0, stream>>>(h1, Wg2, nullptr, Hb, N, MID, MID2);
  agg_kernel<MID2, true><<<aggBlocks, 256, 0, stream>>>(Hb, adj, rowstart, dis, bg2, h2, N);

  // layer 3 (no ELU on GCN branch)
  float* outp = (float*)d_out;
  dim3 g3((N + 63) / 64, OUT_CH / 64);
  gemm64<true ><<<g3, 256, 0, stream>>>(h2, Wl3, bl3, outp, N, MID2, OUT_CH);
  gemm64<false><<<g3, 256, 0, stream>>>(h2, Wg3, nullptr, Hb, N, MID2, OUT_CH);
  agg_kernel<OUT_CH, false><<<aggBlocks, 256, 0, stream>>>(Hb, adj, rowstart, dis, bg3, outp, N);
}

// Round 3
// 1061.507 us; speedup vs baseline: 1.4518x; 1.4518x over previous
//
#include <hip/hip_runtime.h>
#include <hip/hip_bf16.h>
#include <math.h>

#define IN_CH  256
#define MID    512
#define MID2   256
#define OUT_CH 64

typedef __attribute__((ext_vector_type(8))) short s16x8;
typedef __attribute__((ext_vector_type(4))) float f32x4;

// ---------------- CSR build ----------------

__global__ __launch_bounds__(256) void deg_kernel(const int* __restrict__ dst,
                                                  int* __restrict__ cnt, int E) {
  int stride = gridDim.x * blockDim.x;
  for (int e = blockIdx.x * blockDim.x + threadIdx.x; e < E; e += stride)
    atomicAdd(&cnt[dst[e]], 1);
}

__global__ __launch_bounds__(1024) void scan_dis_kernel(const int* __restrict__ cnt,
                                                        int* __restrict__ rowstart,
                                                        float* __restrict__ dis, int N) {
  __shared__ int part[1024];
  int t = threadIdx.x;
  int chunk = (N + 1023) >> 10;
  int lo = t * chunk;
  int hi = lo + chunk; if (hi > N) hi = N; if (lo > N) lo = N;
  int s = 0;
  for (int i = lo; i < hi; ++i) s += cnt[i] + 1;
  part[t] = s;
  __syncthreads();
  for (int off = 1; off < 1024; off <<= 1) {
    int v = (t >= off) ? part[t - off] : 0;
    __syncthreads();
    part[t] += v;
    __syncthreads();
  }
  int base = part[t] - s;  // exclusive prefix
  for (int i = lo; i < hi; ++i) {
    int d = cnt[i] + 1;
    rowstart[i] = base;
    dis[i] = rsqrtf((float)d);
    base += d;
  }
  if (t == 1023) rowstart[N] = part[1023];
}

__global__ __launch_bounds__(256) void fill_adj_kernel(const int* __restrict__ src,
                                                       const int* __restrict__ dst,
                                                       const int* __restrict__ rowstart,
                                                       int* __restrict__ cnt2,
                                                       int* __restrict__ adj,
                                                       int E, int N) {
  int total = E + N;
  int stride = gridDim.x * blockDim.x;
  for (int e = blockIdx.x * blockDim.x + threadIdx.x; e < total; e += stride) {
    int s, d;
    if (e < E) { s = src[e]; d = dst[e]; }
    else       { s = d = e - E; }                 // self-loop
    int pos = rowstart[d] + atomicAdd(&cnt2[d], 1);
    adj[pos] = s;
  }
}

// ---------------- weight split: W[K][Fout] fp32 -> Wt_hi/Wt_lo[Fout][K] bf16 ----------------

__device__ inline unsigned bf16_rne(float v) {
  unsigned u = __float_as_uint(v);
  return (u + 0x7FFFu + ((u >> 16) & 1u)) >> 16;
}

__global__ __launch_bounds__(256) void wsplit_kernel(const float* __restrict__ W,
                                                     short* __restrict__ Wt_hi,
                                                     short* __restrict__ Wt_lo,
                                                     int K, int Fout) {
  int idx = blockIdx.x * 256 + threadIdx.x;
  if (idx >= K * Fout) return;
  int k = idx / Fout, n = idx - k * Fout;
  float v = W[idx];
  unsigned h = bf16_rne(v);
  float hf = __uint_as_float(h << 16);
  unsigned l = bf16_rne(v - hf);
  Wt_hi[(size_t)n * K + k] = (short)h;
  Wt_lo[(size_t)n * K + k] = (short)l;
}

// ---------------- MFMA GEMM, 3-pass bf16 split (~fp32 accuracy) ----------------
// C[Nrows x Fout] = A[Nrows x K] @ W  (+bias), W given pre-split/transposed as
// Bt_hi/Bt_lo [Fout x K] bf16 bits. Requires Fout%128==0, K%64==0.
// 128x128 block tile, BK=64, 4 waves each computing a 64x64 quadrant as 4x4
// fragments of mfma_f32_16x16x32_bf16. LDS tiles [128][64] bf16 with 16B-slot
// XOR swizzle (slot ^= row&7) -> conflict-free ds_read_b128/ds_write_b128.
// A and B fragments use the SAME (lane,elem)->k mapping, so the result is
// invariant to the HW's internal k ordering (kappa_A == kappa_B on CDNA).

template<bool ADD_BIAS>
__global__ __launch_bounds__(256, 2)
void gemm_mfma3(const float* __restrict__ A, const short* __restrict__ Bth,
                const short* __restrict__ Btl, const float* __restrict__ bias,
                float* __restrict__ C, int Nrows, int K, int Fout) {
  __shared__ short lds[4 * 128 * 64];  // 64 KiB: A_hi, A_lo, B_hi, B_lo
  short* Ah = lds;
  short* Al = lds + 8192;
  short* Bh = lds + 16384;
  short* Bl = lds + 24576;

  const int tid  = threadIdx.x;
  const int lane = tid & 63;
  const int wid  = tid >> 6;
  const int wr = wid >> 1, wc = wid & 1;
  const int row0 = blockIdx.x * 128;
  const int col0 = blockIdx.y * 128;

  f32x4 acc[4][4] = {};

  // staging roles: thread t owns row sr=t>>1 (A and B tiles), k-half shalf
  const int sr    = tid >> 1;
  const int shalf = (tid & 1) << 5;   // 0 or 32
  int arow = row0 + sr; if (arow > Nrows - 1) arow = Nrows - 1;  // clamp OOB
  const float* Abase  = A   + (size_t)arow * K + shalf;
  const short* Bhbase = Bth + (size_t)(col0 + sr) * K + shalf;
  const short* Blbase = Btl + (size_t)(col0 + sr) * K + shalf;
  // swizzled LDS write offsets (shorts): row sr, slots (shalf/8+i)^(sr&7)
  int wslot[4];
  #pragma unroll
  for (int i = 0; i < 4; ++i)
    wslot[i] = sr * 64 + ((((shalf >> 3) + i) ^ (sr & 7)) << 3);

  for (int k0 = 0; k0 < K; k0 += 64) {
    // global loads into regs
    float4 av[8];
    const float* ap = Abase + k0;
    #pragma unroll
    for (int i = 0; i < 8; ++i) av[i] = *(const float4*)(ap + i * 4);
    s16x8 rbh[4], rbl[4];
    const short* bp = Bhbase + k0;
    const short* bq = Blbase + k0;
    #pragma unroll
    for (int i = 0; i < 4; ++i) rbh[i] = *(const s16x8*)(bp + i * 8);
    #pragma unroll
    for (int i = 0; i < 4; ++i) rbl[i] = *(const s16x8*)(bq + i * 8);

    __syncthreads();  // previous tile's LDS reads complete

    // split A -> bf16 hi/lo, write swizzled LDS
    #pragma unroll
    for (int i = 0; i < 4; ++i) {
      s16x8 hi, lo;
      #pragma unroll
      for (int j = 0; j < 2; ++j) {
        float4 v = av[i * 2 + j];
        float vv[4] = {v.x, v.y, v.z, v.w};
        #pragma unroll
        for (int m = 0; m < 4; ++m) {
          unsigned h = bf16_rne(vv[m]);
          float hf = __uint_as_float(h << 16);
          unsigned l = bf16_rne(vv[m] - hf);
          hi[j * 4 + m] = (short)h;
          lo[j * 4 + m] = (short)l;
        }
      }
      *(s16x8*)(Ah + wslot[i]) = hi;
      *(s16x8*)(Al + wslot[i]) = lo;
    }
    #pragma unroll
    for (int i = 0; i < 4; ++i) {
      *(s16x8*)(Bh + wslot[i]) = rbh[i];
      *(s16x8*)(Bl + wslot[i]) = rbl[i];
    }
    __syncthreads();  // barrier drains vmcnt+lgkmcnt

    // compute: 2 k-slices x 16 fragments x 3 passes
    #pragma unroll
    for (int ks = 0; ks < 2; ++ks) {
      const int sw = ((((ks << 2) + (lane >> 4)) ^ (lane & 7)) << 3);
      s16x8 fah[4], fal[4], fbh[4], fbl[4];
      #pragma unroll
      for (int mi = 0; mi < 4; ++mi) {
        int base = (wr * 64 + mi * 16 + (lane & 15)) * 64 + sw;
        fah[mi] = *(const s16x8*)(Ah + base);
        fal[mi] = *(const s16x8*)(Al + base);
      }
      #pragma unroll
      for (int ni = 0; ni < 4; ++ni) {
        int base = (wc * 64 + ni * 16 + (lane & 15)) * 64 + sw;
        fbh[ni] = *(const s16x8*)(Bh + base);
        fbl[ni] = *(const s16x8*)(Bl + base);
      }
      #pragma unroll
      for (int mi = 0; mi < 4; ++mi)
        #pragma unroll
        for (int ni = 0; ni < 4; ++ni) {
          acc[mi][ni] = __builtin_amdgcn_mfma_f32_16x16x32_bf16(fah[mi], fbh[ni], acc[mi][ni], 0, 0, 0);
          acc[mi][ni] = __builtin_amdgcn_mfma_f32_16x16x32_bf16(fah[mi], fbl[ni], acc[mi][ni], 0, 0, 0);
          acc[mi][ni] = __builtin_amdgcn_mfma_f32_16x16x32_bf16(fal[mi], fbh[ni], acc[mi][ni], 0, 0, 0);
        }
    }
  }

  // epilogue: C/D mapping col=lane&15, row=(lane>>4)*4+reg   [m89-verified]
  #pragma unroll
  for (int mi = 0; mi < 4; ++mi) {
    #pragma unroll
    for (int r = 0; r < 4; ++r) {
      int rr = row0 + wr * 64 + mi * 16 + (lane >> 4) * 4 + r;
      if (rr >= Nrows) continue;
      #pragma unroll
      for (int ni = 0; ni < 4; ++ni) {
        int cc = col0 + wc * 64 + ni * 16 + (lane & 15);
        float v = acc[mi][ni][r];
        if (ADD_BIAS) v += bias[cc];
        C[(size_t)rr * Fout + cc] = v;
      }
    }
  }
}

// ---------------- fp32 GEMM 64x64 (layer-3, Fout=64) ----------------

template<bool ADD_BIAS>
__global__ __launch_bounds__(256) void gemm64(const float* __restrict__ A,
                                              const float* __restrict__ W,
                                              const float* __restrict__ bias,
                                              float* __restrict__ C,
                                              int Nrows, int K, int Fout) {
  __shared__ float As[16][64];
  __shared__ float Bs[16][64];
  const int tid  = threadIdx.x;
  const int row0 = blockIdx.x * 64;
  const int col0 = blockIdx.y * 64;
  const int tx   = tid & 15;
  const int ty   = tid >> 4;
  const int la_r = tid >> 2;
  const int la_c = (tid & 3) << 2;
  const int lb_r = tid >> 4;
  const int lb_c = (tid & 15) << 2;

  float acc[4][4];
  #pragma unroll
  for (int i = 0; i < 4; ++i)
    #pragma unroll
    for (int j = 0; j < 4; ++j) acc[i][j] = 0.f;

  for (int k0 = 0; k0 < K; k0 += 16) {
    float4 av = make_float4(0.f, 0.f, 0.f, 0.f);
    int ar = row0 + la_r;
    if (ar < Nrows) av = *(const float4*)(A + (size_t)ar * K + (k0 + la_c));
    float4 bv = *(const float4*)(W + (size_t)(k0 + lb_r) * Fout + (col0 + lb_c));
    __syncthreads();
    As[la_c + 0][la_r] = av.x;
    As[la_c + 1][la_r] = av.y;
    As[la_c + 2][la_r] = av.z;
    As[la_c + 3][la_r] = av.w;
    *(float4*)&Bs[lb_r][lb_c] = bv;
    __syncthreads();
    #pragma unroll
    for (int k = 0; k < 16; ++k) {
      float4 a4 = *(const float4*)&As[k][ty << 2];
      float4 b4 = *(const float4*)&Bs[k][tx << 2];
      float a[4] = {a4.x, a4.y, a4.z, a4.w};
      float b[4] = {b4.x, b4.y, b4.z, b4.w};
      #pragma unroll
      for (int i = 0; i < 4; ++i)
        #pragma unroll
        for (int j = 0; j < 4; ++j) acc[i][j] = fmaf(a[i], b[j], acc[i][j]);
    }
  }

  #pragma unroll
  for (int i = 0; i < 4; ++i) {
    int r = row0 + (ty << 2) + i;
    if (r < Nrows) {
      float4 v = make_float4(acc[i][0], acc[i][1], acc[i][2], acc[i][3]);
      if (ADD_BIAS) {
        const float* bp = bias + col0 + (tx << 2);
        v.x += bp[0]; v.y += bp[1]; v.z += bp[2]; v.w += bp[3];
      }
      *(float4*)(C + (size_t)r * Fout + col0 + (tx << 2)) = v;
    }
  }
}

// ---------------- aggregation: one wave per node, edge loop unrolled x4 ----------------

__device__ inline void fma4(float4& a, const float4 q, const float w) {
  a.x = fmaf(q.x, w, a.x); a.y = fmaf(q.y, w, a.y);
  a.z = fmaf(q.z, w, a.z); a.w = fmaf(q.w, w, a.w);
}

template<int F, bool DO_ELU>
__global__ __launch_bounds__(256) void agg_kernel(const float* __restrict__ H,
                                                  const int* __restrict__ adj,
                                                  const int* __restrict__ rowstart,
                                                  const float* __restrict__ dis,
                                                  const float* __restrict__ bias,
                                                  float* __restrict__ out, int N) {
  constexpr int VF = F / 64;
  constexpr int NV = (VF >= 4) ? VF / 4 : 1;
  int node = (int)((blockIdx.x * blockDim.x + threadIdx.x) >> 6);
  int lane = threadIdx.x & 63;
  if (node >= N) return;
  int e = rowstart[node];
  const int end = rowstart[node + 1];

  if constexpr (VF >= 4) {
    float4 acc[NV] = {};
    const char* base = (const char*)H + (size_t)lane * (VF * 4);
    const size_t rstride = (size_t)F * 4;
    for (; e + 4 <= end; e += 4) {
      int s0 = adj[e], s1 = adj[e + 1], s2 = adj[e + 2], s3 = adj[e + 3];
      float w0 = dis[s0], w1 = dis[s1], w2 = dis[s2], w3 = dis[s3];
      const float4* p0 = (const float4*)(base + s0 * rstride);
      const float4* p1 = (const float4*)(base + s1 * rstride);
      const float4* p2 = (const float4*)(base + s2 * rstride);
      const float4* p3 = (const float4*)(base + s3 * rstride);
      #pragma unroll
      for (int v = 0; v < NV; ++v) {
        float4 q0 = p0[v], q1 = p1[v], q2 = p2[v], q3 = p3[v];
        fma4(acc[v], q0, w0); fma4(acc[v], q1, w1);
        fma4(acc[v], q2, w2); fma4(acc[v], q3, w3);
      }
    }
    for (; e < end; ++e) {
      int s = adj[e]; float w = dis[s];
      const float4* p = (const float4*)(base + s * rstride);
      #pragma unroll
      for (int v = 0; v < NV; ++v) fma4(acc[v], p[v], w);
    }
    float di = dis[node];
    float* op = out + (size_t)node * F + lane * VF;
    const float* bp = bias + lane * VF;
    #pragma unroll
    for (int v = 0; v < NV; ++v) {
      float vals[4] = {acc[v].x, acc[v].y, acc[v].z, acc[v].w};
      #pragma unroll
      for (int j = 0; j < 4; ++j) {
        float val = fmaf(vals[j], di, bp[v * 4 + j]);
        if (DO_ELU) val = (val > 0.f) ? val : expm1f(val);
        op[v * 4 + j] += val;
      }
    }
  } else {  // VF == 1 (F == 64)
    float acc = 0.f;
    for (; e + 4 <= end; e += 4) {
      int s0 = adj[e], s1 = adj[e + 1], s2 = adj[e + 2], s3 = adj[e + 3];
      float w0 = dis[s0], w1 = dis[s1], w2 = dis[s2], w3 = dis[s3];
      float q0 = H[(size_t)s0 * F + lane], q1 = H[(size_t)s1 * F + lane];
      float q2 = H[(size_t)s2 * F + lane], q3 = H[(size_t)s3 * F + lane];
      acc = fmaf(q0, w0, acc); acc = fmaf(q1, w1, acc);
      acc = fmaf(q2, w2, acc); acc = fmaf(q3, w3, acc);
    }
    for (; e < end; ++e) {
      int s = adj[e];
      acc = fmaf(H[(size_t)s * F + lane], dis[s], acc);
    }
    float val = fmaf(acc, dis[node], bias[lane]);
    if (DO_ELU) val = (val > 0.f) ? val : expm1f(val);
    out[(size_t)node * F + lane] += val;
  }
}

// ---------------- launch ----------------

static inline char* ws_align(char*& ws, size_t bytes) {
  ws = (char*)(((uintptr_t)ws + 63) & ~(uintptr_t)63);
  char* p = ws;
  ws += bytes;
  return p;
}

extern "C" void kernel_launch(void* const* d_in, const int* in_sizes, int n_in,
                              void* d_out, int out_size, void* d_ws, size_t ws_size,
                              hipStream_t stream) {
  const float* x   = (const float*)d_in[0];
  const int*  eidx = (const int*)d_in[1];
  const float* Wg1 = (const float*)d_in[2];
  const float* bg1 = (const float*)d_in[3];
  const float* Wg2 = (const float*)d_in[4];
  const float* bg2 = (const float*)d_in[5];
  const float* Wg3 = (const float*)d_in[6];
  const float* bg3 = (const float*)d_in[7];
  const float* Wl1 = (const float*)d_in[8];
  const float* bl1 = (const float*)d_in[9];
  const float* Wl2 = (const float*)d_in[10];
  const float* bl2 = (const float*)d_in[11];
  const float* Wl3 = (const float*)d_in[12];
  const float* bl3 = (const float*)d_in[13];

  const int N = in_sizes[0] / IN_CH;
  const int E = in_sizes[1] / 2;
  const int* esrc = eidx;
  const int* edst = eidx + E;

  char* ws = (char*)d_ws;
  float* h1       = (float*)ws_align(ws, (size_t)N * MID  * 4);
  float* h2       = (float*)ws_align(ws, (size_t)N * MID2 * 4);
  float* Hb       = (float*)ws_align(ws, (size_t)N * MID  * 4);
  float* dis      = (float*)ws_align(ws, (size_t)N * 4);
  int*   rowstart = (int*)ws_align(ws, (size_t)(N + 1) * 4);
  int*   cnt      = (int*)ws_align(ws, (size_t)N * 4);
  int*   cnt2     = (int*)ws_align(ws, (size_t)N * 4);
  int*   adj      = (int*)ws_align(ws, (size_t)(E + N) * 4);
  // pre-split transposed weights (bf16 hi/lo), layer 1 and 2
  short* wl1h = (short*)ws_align(ws, (size_t)IN_CH * MID  * 2);
  short* wl1l = (short*)ws_align(ws, (size_t)IN_CH * MID  * 2);
  short* wg1h = (short*)ws_align(ws, (size_t)IN_CH * MID  * 2);
  short* wg1l = (short*)ws_align(ws, (size_t)IN_CH * MID  * 2);
  short* wl2h = (short*)ws_align(ws, (size_t)MID * MID2 * 2);
  short* wl2l = (short*)ws_align(ws, (size_t)MID * MID2 * 2);
  short* wg2h = (short*)ws_align(ws, (size_t)MID * MID2 * 2);
  short* wg2l = (short*)ws_align(ws, (size_t)MID * MID2 * 2);

  hipMemsetAsync(cnt, 0, (size_t)2 * N * 4, stream);  // cnt + cnt2 (contiguous-ish)
  hipMemsetAsync(cnt2, 0, (size_t)N * 4, stream);
  deg_kernel<<<1024, 256, 0, stream>>>(edst, cnt, E);
  scan_dis_kernel<<<1, 1024, 0, stream>>>(cnt, rowstart, dis, N);
  fill_adj_kernel<<<2048, 256, 0, stream>>>(esrc, edst, rowstart, cnt2, adj, E, N);

  // weight split+transpose (tiny)
  {
    int n1 = IN_CH * MID, n2 = MID * MID2;
    wsplit_kernel<<<(n1 + 255) / 256, 256, 0, stream>>>(Wl1, wl1h, wl1l, IN_CH, MID);
    wsplit_kernel<<<(n1 + 255) / 256, 256, 0, stream>>>(Wg1, wg1h, wg1l, IN_CH, MID);
    wsplit_kernel<<<(n2 + 255) / 256, 256, 0, stream>>>(Wl2, wl2h, wl2l, MID, MID2);
    wsplit_kernel<<<(n2 + 255) / 256, 256, 0, stream>>>(Wg2, wg2h, wg2l, MID, MID2);
  }

  int aggBlocks = (N + 3) / 4;
  int rowBlocks = (N + 127) / 128;

  // layer 1: h1 = elu(agg(x@Wg1)+bg1) + x@Wl1 + bl1
  dim3 g1(rowBlocks, MID / 128);
  gemm_mfma3<true ><<<g1, 256, 0, stream>>>(x, wl1h, wl1l, bl1, h1, N, IN_CH, MID);
  gemm_mfma3<false><<<g1, 256, 0, stream>>>(x, wg1h, wg1l, nullptr, Hb, N, IN_CH, MID);
  agg_kernel<MID, true><<<aggBlocks, 256, 0, stream>>>(Hb, adj, rowstart, dis, bg1, h1, N);

  // layer 2
  dim3 g2(rowBlocks, MID2 / 128);
  gemm_mfma3<true ><<<g2, 256, 0, stream>>>(h1, wl2h, wl2l, bl2, h2, N, MID, MID2);
  gemm_mfma3<false><<<g2, 256, 0, stream>>>(h1, wg2h, wg2l, nullptr, Hb, N, MID, MID2);
  agg_kernel<MID2, true><<<aggBlocks, 256, 0, stream>>>(Hb, adj, rowstart, dis, bg2, h2, N);

  // layer 3 (no ELU on GCN branch)
  float* outp = (float*)d_out;
  dim3 g3((N + 63) / 64, OUT_CH / 64);
  gemm64<true ><<<g3, 256, 0, stream>>>(h2, Wl3, bl3, outp, N, MID2, OUT_CH);
  gemm64<false><<<g3, 256, 0, stream>>>(h2, Wg3, nullptr, Hb, N, MID2, OUT_CH);
  agg_kernel<OUT_CH, false><<<aggBlocks, 256, 0, stream>>>(Hb, adj, rowstart, dis, bg3, outp, N);
}

// Round 6
// 893.983 us; speedup vs baseline: 1.7239x; 1.1874x over previous
//
#include <hip/hip_runtime.h>
#include <hip/hip_bf16.h>
#include <math.h>

#define IN_CH  256
#define MID    512
#define MID2   256
#define OUT_CH 64

typedef __attribute__((ext_vector_type(8))) short s16x8;
typedef __attribute__((ext_vector_type(4))) float f32x4;

// ---------------- CSR build ----------------

__global__ __launch_bounds__(256) void deg_kernel(const int* __restrict__ dst,
                                                  int* __restrict__ cnt, int E) {
  int stride = gridDim.x * blockDim.x;
  for (int e = blockIdx.x * blockDim.x + threadIdx.x; e < E; e += stride)
    atomicAdd(&cnt[dst[e]], 1);
}

__global__ __launch_bounds__(1024) void scan_dis_kernel(const int* __restrict__ cnt,
                                                        int* __restrict__ rowstart,
                                                        float* __restrict__ dis, int N) {
  __shared__ int part[1024];
  int t = threadIdx.x;
  int chunk = (N + 1023) >> 10;
  int lo = t * chunk;
  int hi = lo + chunk; if (hi > N) hi = N; if (lo > N) lo = N;
  int s = 0;
  for (int i = lo; i < hi; ++i) s += cnt[i] + 1;
  part[t] = s;
  __syncthreads();
  for (int off = 1; off < 1024; off <<= 1) {
    int v = (t >= off) ? part[t - off] : 0;
    __syncthreads();
    part[t] += v;
    __syncthreads();
  }
  int base = part[t] - s;  // exclusive prefix
  for (int i = lo; i < hi; ++i) {
    int d = cnt[i] + 1;
    rowstart[i] = base;
    dis[i] = rsqrtf((float)d);
    base += d;
  }
  if (t == 1023) rowstart[N] = part[1023];
}

__global__ __launch_bounds__(256) void fill_adj_kernel(const int* __restrict__ src,
                                                       const int* __restrict__ dst,
                                                       const int* __restrict__ rowstart,
                                                       int* __restrict__ cnt2,
                                                       int* __restrict__ adj,
                                                       int E, int N) {
  int total = E + N;
  int stride = gridDim.x * blockDim.x;
  for (int e = blockIdx.x * blockDim.x + threadIdx.x; e < total; e += stride) {
    int s, d;
    if (e < E) { s = src[e]; d = dst[e]; }
    else       { s = d = e - E; }                 // self-loop
    int pos = rowstart[d] + atomicAdd(&cnt2[d], 1);
    adj[pos] = s;
  }
}

// ---------------- weight split into CONCATENATED transposed hi/lo ----------------
// W[K][F] fp32 -> Th/Tl rows [noff+n][k] bf16 bits (row stride K).

__device__ inline unsigned bf16_rne(float v) {
  unsigned u = __float_as_uint(v);
  return (u + 0x7FFFu + ((u >> 16) & 1u)) >> 16;
}

__global__ __launch_bounds__(256) void wsplit_cat(const float* __restrict__ W,
                                                  short* __restrict__ Th,
                                                  short* __restrict__ Tl,
                                                  int K, int F, int noff) {
  int idx = blockIdx.x * 256 + threadIdx.x;
  if (idx >= K * F) return;
  int k = idx / F, n = idx - k * F;
  float v = W[idx];
  unsigned h = bf16_rne(v);
  float hf = __uint_as_float(h << 16);
  unsigned l = bf16_rne(v - hf);
  Th[(size_t)(noff + n) * K + k] = (short)h;
  Tl[(size_t)(noff + n) * K + k] = (short)l;
}

// ---------------- fused dual-output MFMA GEMM, 3-pass bf16 split ----------------
// Weights pre-concatenated: rows [0,F1) = Linear W, rows [F1,2*F1) = GCN W
// (both transposed, split hi/lo, row stride K). Per output row r:
//   cc <  F1 : C1[r][cc]    = acc + bias1[cc]     (fp32)
//   cc >= F1 : C2[r][cc-F1] = acc                 (fp32 or bf16-RNE)
// 128x128 tile, BK=64, 4 waves x (4x4) frags of mfma_f32_16x16x32_bf16.
// XOR-swizzled LDS (slot ^= row&7): conflict-free ds_read/write_b128.
// A and B fragments share the same (lane,elem)->k mapping -> k-order invariant.

template<bool OUT2_BF16>
__global__ __launch_bounds__(256, 2)
void gemm_dual(const float* __restrict__ A, const short* __restrict__ Bth,
               const short* __restrict__ Btl, const float* __restrict__ bias1,
               float* __restrict__ C1, void* __restrict__ C2,
               int Nrows, int K, int F1) {
  __shared__ short lds[4 * 128 * 64];  // 64 KiB: A_hi, A_lo, B_hi, B_lo
  short* Ah = lds;
  short* Al = lds + 8192;
  short* Bh = lds + 16384;
  short* Bl = lds + 24576;

  const int tid  = threadIdx.x;
  const int lane = tid & 63;
  const int wid  = tid >> 6;
  const int wr = wid >> 1, wc = wid & 1;
  const int row0 = blockIdx.x * 128;
  const int col0 = blockIdx.y * 128;

  f32x4 acc[4][4] = {};

  const int sr    = tid >> 1;
  const int shalf = (tid & 1) << 5;   // 0 or 32
  int arow = row0 + sr; if (arow > Nrows - 1) arow = Nrows - 1;  // clamp OOB
  const float* Abase  = A   + (size_t)arow * K + shalf;
  const short* Bhbase = Bth + (size_t)(col0 + sr) * K + shalf;
  const short* Blbase = Btl + (size_t)(col0 + sr) * K + shalf;
  int wslot[4];
  #pragma unroll
  for (int i = 0; i < 4; ++i)
    wslot[i] = sr * 64 + ((((shalf >> 3) + i) ^ (sr & 7)) << 3);

  for (int k0 = 0; k0 < K; k0 += 64) {
    float4 av[8];
    const float* ap = Abase + k0;
    #pragma unroll
    for (int i = 0; i < 8; ++i) av[i] = *(const float4*)(ap + i * 4);
    s16x8 rbh[4], rbl[4];
    const short* bp = Bhbase + k0;
    const short* bq = Blbase + k0;
    #pragma unroll
    for (int i = 0; i < 4; ++i) rbh[i] = *(const s16x8*)(bp + i * 8);
    #pragma unroll
    for (int i = 0; i < 4; ++i) rbl[i] = *(const s16x8*)(bq + i * 8);

    __syncthreads();

    #pragma unroll
    for (int i = 0; i < 4; ++i) {
      s16x8 hi, lo;
      #pragma unroll
      for (int j = 0; j < 2; ++j) {
        float4 v = av[i * 2 + j];
        float vv[4] = {v.x, v.y, v.z, v.w};
        #pragma unroll
        for (int m = 0; m < 4; ++m) {
          unsigned h = bf16_rne(vv[m]);
          float hf = __uint_as_float(h << 16);
          unsigned l = bf16_rne(vv[m] - hf);
          hi[j * 4 + m] = (short)h;
          lo[j * 4 + m] = (short)l;
        }
      }
      *(s16x8*)(Ah + wslot[i]) = hi;
      *(s16x8*)(Al + wslot[i]) = lo;
    }
    #pragma unroll
    for (int i = 0; i < 4; ++i) {
      *(s16x8*)(Bh + wslot[i]) = rbh[i];
      *(s16x8*)(Bl + wslot[i]) = rbl[i];
    }
    __syncthreads();

    #pragma unroll
    for (int ks = 0; ks < 2; ++ks) {
      const int sw = ((((ks << 2) + (lane >> 4)) ^ (lane & 7)) << 3);
      s16x8 fah[4], fal[4], fbh[4], fbl[4];
      #pragma unroll
      for (int mi = 0; mi < 4; ++mi) {
        int base = (wr * 64 + mi * 16 + (lane & 15)) * 64 + sw;
        fah[mi] = *(const s16x8*)(Ah + base);
        fal[mi] = *(const s16x8*)(Al + base);
      }
      #pragma unroll
      for (int ni = 0; ni < 4; ++ni) {
        int base = (wc * 64 + ni * 16 + (lane & 15)) * 64 + sw;
        fbh[ni] = *(const s16x8*)(Bh + base);
        fbl[ni] = *(const s16x8*)(Bl + base);
      }
      #pragma unroll
      for (int mi = 0; mi < 4; ++mi)
        #pragma unroll
        for (int ni = 0; ni < 4; ++ni) {
          acc[mi][ni] = __builtin_amdgcn_mfma_f32_16x16x32_bf16(fah[mi], fbh[ni], acc[mi][ni], 0, 0, 0);
          acc[mi][ni] = __builtin_amdgcn_mfma_f32_16x16x32_bf16(fah[mi], fbl[ni], acc[mi][ni], 0, 0, 0);
          acc[mi][ni] = __builtin_amdgcn_mfma_f32_16x16x32_bf16(fal[mi], fbh[ni], acc[mi][ni], 0, 0, 0);
        }
    }
  }

  // epilogue: C/D mapping col=lane&15, row=(lane>>4)*4+reg   [m89-verified]
  #pragma unroll
  for (int mi = 0; mi < 4; ++mi) {
    #pragma unroll
    for (int r = 0; r < 4; ++r) {
      int rr = row0 + wr * 64 + mi * 16 + (lane >> 4) * 4 + r;
      if (rr >= Nrows) continue;
      #pragma unroll
      for (int ni = 0; ni < 4; ++ni) {
        int cc = col0 + wc * 64 + ni * 16 + (lane & 15);
        float v = acc[mi][ni][r];
        if (cc < F1) {
          C1[(size_t)rr * F1 + cc] = v + bias1[cc];
        } else {
          int c2 = cc - F1;
          if (OUT2_BF16)
            ((unsigned short*)C2)[(size_t)rr * F1 + c2] = (unsigned short)bf16_rne(v);
          else
            ((float*)C2)[(size_t)rr * F1 + c2] = v;
        }
      }
    }
  }
}

// ---------------- aggregation (bf16 gather): one wave per node ----------------
// out[i] += epilogue( dis[i] * sum_s Hbf16[s]*dis[s] + bias )

template<int F, bool DO_ELU>
__global__ __launch_bounds__(256) void agg_bf16(const unsigned short* __restrict__ H,
                                                const int* __restrict__ adj,
                                                const int* __restrict__ rowstart,
                                                const float* __restrict__ dis,
                                                const float* __restrict__ bias,
                                                float* __restrict__ out, int N) {
  constexpr int VF = F / 64;  // bf16 channels per lane (4 or 8)
  typedef __attribute__((ext_vector_type(VF))) unsigned short uvec;
  int node = (int)((blockIdx.x * blockDim.x + threadIdx.x) >> 6);
  int lane = threadIdx.x & 63;
  if (node >= N) return;
  int e = rowstart[node];
  const int end = rowstart[node + 1];

  float acc[VF] = {};
  const unsigned short* base = H + (size_t)lane * VF;
  for (; e + 4 <= end; e += 4) {
    int s0 = adj[e], s1 = adj[e + 1], s2 = adj[e + 2], s3 = adj[e + 3];
    float w0 = dis[s0], w1 = dis[s1], w2 = dis[s2], w3 = dis[s3];
    uvec v0 = *(const uvec*)(base + (size_t)s0 * F);
    uvec v1 = *(const uvec*)(base + (size_t)s1 * F);
    uvec v2 = *(const uvec*)(base + (size_t)s2 * F);
    uvec v3 = *(const uvec*)(base + (size_t)s3 * F);
    #pragma unroll
    for (int j = 0; j < VF; ++j) {
      acc[j] = fmaf(__uint_as_float((unsigned)v0[j] << 16), w0, acc[j]);
      acc[j] = fmaf(__uint_as_float((unsigned)v1[j] << 16), w1, acc[j]);
      acc[j] = fmaf(__uint_as_float((unsigned)v2[j] << 16), w2, acc[j]);
      acc[j] = fmaf(__uint_as_float((unsigned)v3[j] << 16), w3, acc[j]);
    }
  }
  for (; e < end; ++e) {
    int s = adj[e]; float w = dis[s];
    uvec v = *(const uvec*)(base + (size_t)s * F);
    #pragma unroll
    for (int j = 0; j < VF; ++j)
      acc[j] = fmaf(__uint_as_float((unsigned)v[j] << 16), w, acc[j]);
  }

  float di = dis[node];
  float* op = out + (size_t)node * F + lane * VF;
  const float* bp = bias + lane * VF;
  #pragma unroll
  for (int j = 0; j < VF; ++j) {
    float val = fmaf(acc[j], di, bp[j]);
    if (DO_ELU) val = (val > 0.f) ? val : expm1f(val);
    op[j] += val;
  }
}

// ---------------- aggregation (fp32 gather, layer-3 F=64) ----------------

template<int F, bool DO_ELU>
__global__ __launch_bounds__(256) void agg_f32(const float* __restrict__ H,
                                               const int* __restrict__ adj,
                                               const int* __restrict__ rowstart,
                                               const float* __restrict__ dis,
                                               const float* __restrict__ bias,
                                               float* __restrict__ out, int N) {
  int node = (int)((blockIdx.x * blockDim.x + threadIdx.x) >> 6);
  int lane = threadIdx.x & 63;
  if (node >= N) return;
  int e = rowstart[node];
  const int end = rowstart[node + 1];
  float acc = 0.f;
  for (; e + 4 <= end; e += 4) {
    int s0 = adj[e], s1 = adj[e + 1], s2 = adj[e + 2], s3 = adj[e + 3];
    float w0 = dis[s0], w1 = dis[s1], w2 = dis[s2], w3 = dis[s3];
    float q0 = H[(size_t)s0 * F + lane], q1 = H[(size_t)s1 * F + lane];
    float q2 = H[(size_t)s2 * F + lane], q3 = H[(size_t)s3 * F + lane];
    acc = fmaf(q0, w0, acc); acc = fmaf(q1, w1, acc);
    acc = fmaf(q2, w2, acc); acc = fmaf(q3, w3, acc);
  }
  for (; e < end; ++e) {
    int s = adj[e];
    acc = fmaf(H[(size_t)s * F + lane], dis[s], acc);
  }
  float val = fmaf(acc, dis[node], bias[lane]);
  if (DO_ELU) val = (val > 0.f) ? val : expm1f(val);
  out[(size_t)node * F + lane] += val;
}

// ---------------- launch ----------------

static inline char* ws_align(char*& ws, size_t bytes) {
  ws = (char*)(((uintptr_t)ws + 63) & ~(uintptr_t)63);
  char* p = ws;
  ws += bytes;
  return p;
}

extern "C" void kernel_launch(void* const* d_in, const int* in_sizes, int n_in,
                              void* d_out, int out_size, void* d_ws, size_t ws_size,
                              hipStream_t stream) {
  const float* x   = (const float*)d_in[0];
  const int*  eidx = (const int*)d_in[1];
  const float* Wg1 = (const float*)d_in[2];
  const float* bg1 = (const float*)d_in[3];
  const float* Wg2 = (const float*)d_in[4];
  const float* bg2 = (const float*)d_in[5];
  const float* Wg3 = (const float*)d_in[6];
  const float* bg3 = (const float*)d_in[7];
  const float* Wl1 = (const float*)d_in[8];
  const float* bl1 = (const float*)d_in[9];
  const float* Wl2 = (const float*)d_in[10];
  const float* bl2 = (const float*)d_in[11];
  const float* Wl3 = (const float*)d_in[12];
  const float* bl3 = (const float*)d_in[13];

  const int N = in_sizes[0] / IN_CH;
  const int E = in_sizes[1] / 2;
  const int* esrc = eidx;
  const int* edst = eidx + E;

  char* ws = (char*)d_ws;
  float* h1   = (float*)ws_align(ws, (size_t)N * MID  * 4);
  float* h2   = (float*)ws_align(ws, (size_t)N * MID2 * 4);
  unsigned short* Hbf = (unsigned short*)ws_align(ws, (size_t)N * MID * 2);  // bf16 GCN branch (layers 1-2)
  float* Hb3  = (float*)ws_align(ws, (size_t)N * OUT_CH * 4);               // fp32 GCN branch (layer 3)
  float* dis      = (float*)ws_align(ws, (size_t)N * 4);
  int*   rowstart = (int*)ws_align(ws, (size_t)(N + 1) * 4);
  int*   cnt      = (int*)ws_align(ws, (size_t)N * 4);
  int*   cnt2     = (int*)ws_align(ws, (size_t)N * 4);
  int*   adj      = (int*)ws_align(ws, (size_t)(E + N) * 4);
  // concatenated split weights: layer1 [1024][256], layer2 [512][512], layer3 [128][256]
  short* w1h = (short*)ws_align(ws, (size_t)1024 * IN_CH * 2);
  short* w1l = (short*)ws_align(ws, (size_t)1024 * IN_CH * 2);
  short* w2h = (short*)ws_align(ws, (size_t)512 * MID * 2);
  short* w2l = (short*)ws_align(ws, (size_t)512 * MID * 2);
  short* w3h = (short*)ws_align(ws, (size_t)128 * MID2 * 2);
  short* w3l = (short*)ws_align(ws, (size_t)128 * MID2 * 2);

  hipMemsetAsync(cnt, 0, (size_t)N * 4, stream);
  hipMemsetAsync(cnt2, 0, (size_t)N * 4, stream);
  deg_kernel<<<1024, 256, 0, stream>>>(edst, cnt, E);
  scan_dis_kernel<<<1, 1024, 0, stream>>>(cnt, rowstart, dis, N);
  fill_adj_kernel<<<2048, 256, 0, stream>>>(esrc, edst, rowstart, cnt2, adj, E, N);

  // weight split + transpose + concat (tiny)
  {
    int n1 = IN_CH * MID, n2 = MID * MID2, n3 = MID2 * OUT_CH;
    wsplit_cat<<<(n1 + 255) / 256, 256, 0, stream>>>(Wl1, w1h, w1l, IN_CH, MID, 0);
    wsplit_cat<<<(n1 + 255) / 256, 256, 0, stream>>>(Wg1, w1h, w1l, IN_CH, MID, MID);
    wsplit_cat<<<(n2 + 255) / 256, 256, 0, stream>>>(Wl2, w2h, w2l, MID, MID2, 0);
    wsplit_cat<<<(n2 + 255) / 256, 256, 0, stream>>>(Wg2, w2h, w2l, MID, MID2, MID2);
    wsplit_cat<<<(n3 + 255) / 256, 256, 0, stream>>>(Wl3, w3h, w3l, MID2, OUT_CH, 0);
    wsplit_cat<<<(n3 + 255) / 256, 256, 0, stream>>>(Wg3, w3h, w3l, MID2, OUT_CH, OUT_CH);
  }

  const int aggBlocks = (N + 3) / 4;
  const int rowBlocks = (N + 127) / 128;

  // layer 1: h1 = elu(agg(x@Wg1)+bg1) + (x@Wl1 + bl1)
  dim3 g1(rowBlocks, (2 * MID) / 128);
  gemm_dual<true><<<g1, 256, 0, stream>>>(x, w1h, w1l, bl1, h1, Hbf, N, IN_CH, MID);
  agg_bf16<MID, true><<<aggBlocks, 256, 0, stream>>>(Hbf, adj, rowstart, dis, bg1, h1, N);

  // layer 2
  dim3 g2(rowBlocks, (2 * MID2) / 128);
  gemm_dual<true><<<g2, 256, 0, stream>>>(h1, w2h, w2l, bl2, h2, Hbf, N, MID, MID2);
  agg_bf16<MID2, true><<<aggBlocks, 256, 0, stream>>>(Hbf, adj, rowstart, dis, bg2, h2, N);

  // layer 3 (no ELU on GCN branch; fp32 gather into final output)
  float* outp = (float*)d_out;
  dim3 g3(rowBlocks, (2 * OUT_CH) / 128);
  gemm_dual<false><<<g3, 256, 0, stream>>>(h2, w3h, w3l, bl3, outp, Hb3, N, MID2, OUT_CH);
  agg_f32<OUT_CH, false><<<aggBlocks, 256, 0, stream>>>(Hb3, adj, rowstart, dis, bg3, outp, N);
}

// Round 9
// 871.179 us; speedup vs baseline: 1.7690x; 1.0262x over previous
//
#include <hip/hip_runtime.h>
#include <hip/hip_bf16.h>
#include <math.h>

#define IN_CH  256
#define MID    512
#define MID2   256
#define OUT_CH 64

typedef __attribute__((ext_vector_type(8))) short s16x8;
typedef __attribute__((ext_vector_type(8))) unsigned short u16x8;
typedef __attribute__((ext_vector_type(4))) unsigned short u16x4;
typedef __attribute__((ext_vector_type(4))) float f32x4;

// ---------------- CSR build ----------------

__global__ __launch_bounds__(256) void deg_kernel(const int* __restrict__ dst,
                                                  int* __restrict__ cnt, int E) {
  int stride = gridDim.x * blockDim.x;
  for (int e = blockIdx.x * blockDim.x + threadIdx.x; e < E; e += stride)
    atomicAdd(&cnt[dst[e]], 1);
}

__global__ __launch_bounds__(1024) void scan_dis_kernel(const int* __restrict__ cnt,
                                                        int* __restrict__ rowstart,
                                                        float* __restrict__ dis, int N) {
  __shared__ int part[1024];
  int t = threadIdx.x;
  int chunk = (N + 1023) >> 10;
  int lo = t * chunk;
  int hi = lo + chunk; if (hi > N) hi = N; if (lo > N) lo = N;
  int s = 0;
  for (int i = lo; i < hi; ++i) s += cnt[i] + 1;
  part[t] = s;
  __syncthreads();
  for (int off = 1; off < 1024; off <<= 1) {
    int v = (t >= off) ? part[t - off] : 0;
    __syncthreads();
    part[t] += v;
    __syncthreads();
  }
  int base = part[t] - s;  // exclusive prefix
  for (int i = lo; i < hi; ++i) {
    int d = cnt[i] + 1;
    rowstart[i] = base;
    dis[i] = rsqrtf((float)d);
    base += d;
  }
  if (t == 1023) rowstart[N] = part[1023];
}

__global__ __launch_bounds__(256) void fill_adj_kernel(const int* __restrict__ src,
                                                       const int* __restrict__ dst,
                                                       const int* __restrict__ rowstart,
                                                       int* __restrict__ cnt2,
                                                       int* __restrict__ adj,
                                                       int E, int N) {
  int total = E + N;
  int stride = gridDim.x * blockDim.x;
  for (int e = blockIdx.x * blockDim.x + threadIdx.x; e < total; e += stride) {
    int s, d;
    if (e < E) { s = src[e]; d = dst[e]; }
    else       { s = d = e - E; }                 // self-loop
    int pos = rowstart[d] + atomicAdd(&cnt2[d], 1);
    adj[pos] = s;
  }
}

// ---------------- bf16 split helpers ----------------

__device__ inline unsigned bf16_rne(float v) {
  unsigned u = __float_as_uint(v);
  return (u + 0x7FFFu + ((u >> 16) & 1u)) >> 16;
}

// W[K][F] fp32 -> Th/Tl rows [noff+n][k] bf16 bits (row stride K)
__global__ __launch_bounds__(256) void wsplit_cat(const float* __restrict__ W,
                                                  unsigned short* __restrict__ Th,
                                                  unsigned short* __restrict__ Tl,
                                                  int K, int F, int noff) {
  int idx = blockIdx.x * 256 + threadIdx.x;
  if (idx >= K * F) return;
  int k = idx / F, n = idx - k * F;
  float v = W[idx];
  unsigned h = bf16_rne(v);
  float hf = __uint_as_float(h << 16);
  unsigned l = bf16_rne(v - hf);
  Th[(size_t)(noff + n) * K + k] = (unsigned short)h;
  Tl[(size_t)(noff + n) * K + k] = (unsigned short)l;
}

// X fp32 -> Xh/Xl bf16 pair, elementwise (8 elems/thread)
__global__ __launch_bounds__(256) void split_pair(const float* __restrict__ X,
                                                  unsigned short* __restrict__ Xh,
                                                  unsigned short* __restrict__ Xl,
                                                  int n8) {
  int i = blockIdx.x * 256 + threadIdx.x;
  if (i >= n8) return;
  const float4* xp = (const float4*)X + (size_t)i * 2;
  float4 a = xp[0], b = xp[1];
  float vv[8] = {a.x, a.y, a.z, a.w, b.x, b.y, b.z, b.w};
  u16x8 hv, lv;
  #pragma unroll
  for (int j = 0; j < 8; ++j) {
    unsigned h = bf16_rne(vv[j]);
    float hf = __uint_as_float(h << 16);
    unsigned l = bf16_rne(vv[j] - hf);
    hv[j] = (unsigned short)h;
    lv[j] = (unsigned short)l;
  }
  ((u16x8*)Xh)[i] = hv;
  ((u16x8*)Xl)[i] = lv;
}

// ---------------- MFMA GEMM with PRE-SPLIT bf16 A (3-pass fp32 emulation) ----------
// A given as Agh/Agl [Nrows][K] bf16 pairs; B as Bgh/Bgl [Fcols][K] (transposed).
// 128x128 tile, BK=64, 4 waves x 4x4 frags of mfma_f32_16x16x32_bf16.
// XOR-swizzled LDS (16B slot ^= row&7): conflict-free ds_read/write_b128.
// A and B fragments share the same (lane,elem)->k mapping -> k-order invariant.
// MODE 0: C1w[rr*F1+cc] = v + bias[cc]                       (all cols)
// MODE 1: t = C1r[] + elu(v + bias[cc]); O2h/O2l[] = split(t) (all cols)
// MODE 2: cc<F1: C1w = v+bias; else O2h[cc-F1] = bf16(v)      (dual)
// MODE 3: cc<F1: C1w = v+bias; else O2f[cc-F1] = v            (dual)

template<int MODE>
__global__ __launch_bounds__(256, 2)
void gemm_ps(const unsigned short* __restrict__ Agh, const unsigned short* __restrict__ Agl,
             const unsigned short* __restrict__ Bgh, const unsigned short* __restrict__ Bgl,
             const float* __restrict__ bias,
             const float* __restrict__ C1r, float* __restrict__ C1w,
             unsigned short* __restrict__ O2h, unsigned short* __restrict__ O2l,
             float* __restrict__ O2f,
             int Nrows, int K, int F1) {
  __shared__ unsigned short lds[4 * 128 * 64];  // 64 KiB: A_hi, A_lo, B_hi, B_lo
  unsigned short* Ah = lds;
  unsigned short* Al = lds + 8192;
  unsigned short* Bh = lds + 16384;
  unsigned short* Bl = lds + 24576;

  const int tid  = threadIdx.x;
  const int lane = tid & 63;
  const int wid  = tid >> 6;
  const int wr = wid >> 1, wc = wid & 1;
  const int row0 = blockIdx.x * 128;
  const int col0 = blockIdx.y * 128;

  f32x4 acc[4][4] = {};

  const int sr    = tid >> 1;
  const int shalf = (tid & 1) << 5;   // k-offset 0 or 32
  int arow = row0 + sr; if (arow > Nrows - 1) arow = Nrows - 1;  // clamp OOB
  const unsigned short* Ahb = Agh + (size_t)arow * K + shalf;
  const unsigned short* Alb = Agl + (size_t)arow * K + shalf;
  const unsigned short* Bhb = Bgh + (size_t)(col0 + sr) * K + shalf;
  const unsigned short* Blb = Bgl + (size_t)(col0 + sr) * K + shalf;
  int wslot[4];
  #pragma unroll
  for (int i = 0; i < 4; ++i)
    wslot[i] = sr * 64 + ((((shalf >> 3) + i) ^ (sr & 7)) << 3);

  for (int k0 = 0; k0 < K; k0 += 64) {
    u16x8 rah[4], ral[4], rbh[4], rbl[4];
    #pragma unroll
    for (int i = 0; i < 4; ++i) rah[i] = *(const u16x8*)(Ahb + k0 + i * 8);
    #pragma unroll
    for (int i = 0; i < 4; ++i) ral[i] = *(const u16x8*)(Alb + k0 + i * 8);
    #pragma unroll
    for (int i = 0; i < 4; ++i) rbh[i] = *(const u16x8*)(Bhb + k0 + i * 8);
    #pragma unroll
    for (int i = 0; i < 4; ++i) rbl[i] = *(const u16x8*)(Blb + k0 + i * 8);

    __syncthreads();  // previous tile's LDS reads complete
    #pragma unroll
    for (int i = 0; i < 4; ++i) {
      *(u16x8*)(Ah + wslot[i]) = rah[i];
      *(u16x8*)(Al + wslot[i]) = ral[i];
      *(u16x8*)(Bh + wslot[i]) = rbh[i];
      *(u16x8*)(Bl + wslot[i]) = rbl[i];
    }
    __syncthreads();

    #pragma unroll
    for (int ks = 0; ks < 2; ++ks) {
      const int sw = ((((ks << 2) + (lane >> 4)) ^ (lane & 7)) << 3);
      s16x8 fah[4], fal[4], fbh[4], fbl[4];
      #pragma unroll
      for (int mi = 0; mi < 4; ++mi) {
        int base = (wr * 64 + mi * 16 + (lane & 15)) * 64 + sw;
        fah[mi] = *(const s16x8*)(Ah + base);
        fal[mi] = *(const s16x8*)(Al + base);
      }
      #pragma unroll
      for (int ni = 0; ni < 4; ++ni) {
        int base = (wc * 64 + ni * 16 + (lane & 15)) * 64 + sw;
        fbh[ni] = *(const s16x8*)(Bh + base);
        fbl[ni] = *(const s16x8*)(Bl + base);
      }
      #pragma unroll
      for (int mi = 0; mi < 4; ++mi)
        #pragma unroll
        for (int ni = 0; ni < 4; ++ni) {
          acc[mi][ni] = __builtin_amdgcn_mfma_f32_16x16x32_bf16(fah[mi], fbh[ni], acc[mi][ni], 0, 0, 0);
          acc[mi][ni] = __builtin_amdgcn_mfma_f32_16x16x32_bf16(fah[mi], fbl[ni], acc[mi][ni], 0, 0, 0);
          acc[mi][ni] = __builtin_amdgcn_mfma_f32_16x16x32_bf16(fal[mi], fbh[ni], acc[mi][ni], 0, 0, 0);
        }
    }
  }

  // epilogue: C/D mapping col=lane&15, row=(lane>>4)*4+reg   [m89-verified]
  #pragma unroll
  for (int mi = 0; mi < 4; ++mi) {
    #pragma unroll
    for (int r = 0; r < 4; ++r) {
      int rr = row0 + wr * 64 + mi * 16 + (lane >> 4) * 4 + r;
      if (rr >= Nrows) continue;
      #pragma unroll
      for (int ni = 0; ni < 4; ++ni) {
        int cc = col0 + wc * 64 + ni * 16 + (lane & 15);
        float v = acc[mi][ni][r];
        if (MODE == 0) {
          C1w[(size_t)rr * F1 + cc] = v + bias[cc];
        } else if (MODE == 1) {
          float t = v + bias[cc];
          t = (t > 0.f) ? t : expm1f(t);
          t += C1r[(size_t)rr * F1 + cc];
          size_t idx = (size_t)rr * F1 + cc;
          unsigned h = bf16_rne(t);
          float hf = __uint_as_float(h << 16);
          unsigned l = bf16_rne(t - hf);
          O2h[idx] = (unsigned short)h;
          O2l[idx] = (unsigned short)l;
        } else {
          if (cc < F1) {
            C1w[(size_t)rr * F1 + cc] = v + bias[cc];
          } else {
            size_t idx = (size_t)rr * F1 + (cc - F1);
            if (MODE == 2) O2h[idx] = (unsigned short)bf16_rne(v);
            else           O2f[idx] = v;
          }
        }
      }
    }
  }
}

// ---------------- aggregation kernels (one wave per node) ----------------

// z = dis[i] * sum_s H[s]*dis[s]  -> split bf16 pair (no bias/elu/add)
template<int F>
__global__ __launch_bounds__(256) void agg_split(const unsigned short* __restrict__ H,
                                                 const int* __restrict__ adj,
                                                 const int* __restrict__ rowstart,
                                                 const float* __restrict__ dis,
                                                 unsigned short* __restrict__ Zh,
                                                 unsigned short* __restrict__ Zl, int N) {
  constexpr int VF = F / 64;  // 4 for F=256
  typedef __attribute__((ext_vector_type(VF))) unsigned short uvec;
  int node = (int)((blockIdx.x * blockDim.x + threadIdx.x) >> 6);
  int lane = threadIdx.x & 63;
  if (node >= N) return;
  int e = rowstart[node];
  const int end = rowstart[node + 1];

  float acc[VF] = {};
  const unsigned short* base = H + (size_t)lane * VF;
  for (; e + 4 <= end; e += 4) {
    int s0 = adj[e], s1 = adj[e + 1], s2 = adj[e + 2], s3 = adj[e + 3];
    float w0 = dis[s0], w1 = dis[s1], w2 = dis[s2], w3 = dis[s3];
    uvec v0 = *(const uvec*)(base + (size_t)s0 * F);
    uvec v1 = *(const uvec*)(base + (size_t)s1 * F);
    uvec v2 = *(const uvec*)(base + (size_t)s2 * F);
    uvec v3 = *(const uvec*)(base + (size_t)s3 * F);
    #pragma unroll
    for (int j = 0; j < VF; ++j) {
      acc[j] = fmaf(__uint_as_float((unsigned)v0[j] << 16), w0, acc[j]);
      acc[j] = fmaf(__uint_as_float((unsigned)v1[j] << 16), w1, acc[j]);
      acc[j] = fmaf(__uint_as_float((unsigned)v2[j] << 16), w2, acc[j]);
      acc[j] = fmaf(__uint_as_float((unsigned)v3[j] << 16), w3, acc[j]);
    }
  }
  for (; e < end; ++e) {
    int s = adj[e]; float w = dis[s];
    uvec v = *(const uvec*)(base + (size_t)s * F);
    #pragma unroll
    for (int j = 0; j < VF; ++j)
      acc[j] = fmaf(__uint_as_float((unsigned)v[j] << 16), w, acc[j]);
  }

  float di = dis[node];
  uvec hv, lv;
  #pragma unroll
  for (int j = 0; j < VF; ++j) {
    float val = acc[j] * di;
    unsigned h = bf16_rne(val);
    float hf = __uint_as_float(h << 16);
    unsigned l = bf16_rne(val - hf);
    hv[j] = (unsigned short)h;
    lv[j] = (unsigned short)l;
  }
  *(uvec*)(Zh + (size_t)node * F + lane * VF) = hv;
  *(uvec*)(Zl + (size_t)node * F + lane * VF) = lv;
}

// t = elu(dis[i]*sum + bias) + lin[i]  -> split bf16 pair (layer-2 output h2)
template<int F>
__global__ __launch_bounds__(256) void agg_addsplit(const unsigned short* __restrict__ H,
                                                    const int* __restrict__ adj,
                                                    const int* __restrict__ rowstart,
                                                    const float* __restrict__ dis,
                                                    const float* __restrict__ bias,
                                                    const float* __restrict__ lin,
                                                    unsigned short* __restrict__ Zh,
                                                    unsigned short* __restrict__ Zl, int N) {
  constexpr int VF = F / 64;
  typedef __attribute__((ext_vector_type(VF))) unsigned short uvec;
  int node = (int)((blockIdx.x * blockDim.x + threadIdx.x) >> 6);
  int lane = threadIdx.x & 63;
  if (node >= N) return;
  int e = rowstart[node];
  const int end = rowstart[node + 1];

  float acc[VF] = {};
  const unsigned short* base = H + (size_t)lane * VF;
  for (; e + 4 <= end; e += 4) {
    int s0 = adj[e], s1 = adj[e + 1], s2 = adj[e + 2], s3 = adj[e + 3];
    float w0 = dis[s0], w1 = dis[s1], w2 = dis[s2], w3 = dis[s3];
    uvec v0 = *(const uvec*)(base + (size_t)s0 * F);
    uvec v1 = *(const uvec*)(base + (size_t)s1 * F);
    uvec v2 = *(const uvec*)(base + (size_t)s2 * F);
    uvec v3 = *(const uvec*)(base + (size_t)s3 * F);
    #pragma unroll
    for (int j = 0; j < VF; ++j) {
      acc[j] = fmaf(__uint_as_float((unsigned)v0[j] << 16), w0, acc[j]);
      acc[j] = fmaf(__uint_as_float((unsigned)v1[j] << 16), w1, acc[j]);
      acc[j] = fmaf(__uint_as_float((unsigned)v2[j] << 16), w2, acc[j]);
      acc[j] = fmaf(__uint_as_float((unsigned)v3[j] << 16), w3, acc[j]);
    }
  }
  for (; e < end; ++e) {
    int s = adj[e]; float w = dis[s];
    uvec v = *(const uvec*)(base + (size_t)s * F);
    #pragma unroll
    for (int j = 0; j < VF; ++j)
      acc[j] = fmaf(__uint_as_float((unsigned)v[j] << 16), w, acc[j]);
  }

  float di = dis[node];
  const float* bp = bias + lane * VF;
  const float* lp = lin + (size_t)node * F + lane * VF;
  uvec hv, lv;
  #pragma unroll
  for (int j = 0; j < VF; ++j) {
    float val = fmaf(acc[j], di, bp[j]);
    val = (val > 0.f) ? val : expm1f(val);
    val += lp[j];
    unsigned h = bf16_rne(val);
    float hf = __uint_as_float(h << 16);
    unsigned l = bf16_rne(val - hf);
    hv[j] = (unsigned short)h;
    lv[j] = (unsigned short)l;
  }
  *(uvec*)(Zh + (size_t)node * F + lane * VF) = hv;
  *(uvec*)(Zl + (size_t)node * F + lane * VF) = lv;
}

// fp32 gather, layer-3 F=64: out += dis[i]*sum + bias
template<int F>
__global__ __launch_bounds__(256) void agg_f32(const float* __restrict__ H,
                                               const int* __restrict__ adj,
                                               const int* __restrict__ rowstart,
                                               const float* __restrict__ dis,
                                               const float* __restrict__ bias,
                                               float* __restrict__ out, int N) {
  int node = (int)((blockIdx.x * blockDim.x + threadIdx.x) >> 6);
  int lane = threadIdx.x & 63;
  if (node >= N) return;
  int e = rowstart[node];
  const int end = rowstart[node + 1];
  float acc = 0.f;
  for (; e + 4 <= end; e += 4) {
    int s0 = adj[e], s1 = adj[e + 1], s2 = adj[e + 2], s3 = adj[e + 3];
    float w0 = dis[s0], w1 = dis[s1], w2 = dis[s2], w3 = dis[s3];
    float q0 = H[(size_t)s0 * F + lane], q1 = H[(size_t)s1 * F + lane];
    float q2 = H[(size_t)s2 * F + lane], q3 = H[(size_t)s3 * F + lane];
    acc = fmaf(q0, w0, acc); acc = fmaf(q1, w1, acc);
    acc = fmaf(q2, w2, acc); acc = fmaf(q3, w3, acc);
  }
  for (; e < end; ++e) {
    int s = adj[e];
    acc = fmaf(H[(size_t)s * F + lane], dis[s], acc);
  }
  out[(size_t)node * F + lane] += fmaf(acc, dis[node], bias[lane]);
}

// ---------------- launch ----------------

static inline char* ws_align(char*& ws, size_t bytes) {
  ws = (char*)(((uintptr_t)ws + 255) & ~(uintptr_t)255);
  char* p = ws;
  ws += bytes;
  return p;
}

extern "C" void kernel_launch(void* const* d_in, const int* in_sizes, int n_in,
                              void* d_out, int out_size, void* d_ws, size_t ws_size,
                              hipStream_t stream) {
  const float* x   = (const float*)d_in[0];
  const int*  eidx = (const int*)d_in[1];
  const float* Wg1 = (const float*)d_in[2];
  const float* bg1 = (const float*)d_in[3];
  const float* Wg2 = (const float*)d_in[4];
  const float* bg2 = (const float*)d_in[5];
  const float* Wg3 = (const float*)d_in[6];
  const float* bg3 = (const float*)d_in[7];
  const float* Wl1 = (const float*)d_in[8];
  const float* bl1 = (const float*)d_in[9];
  const float* Wl2 = (const float*)d_in[10];
  const float* bl2 = (const float*)d_in[11];
  const float* Wl3 = (const float*)d_in[12];
  const float* bl3 = (const float*)d_in[13];

  const int N = in_sizes[0] / IN_CH;
  const int E = in_sizes[1] / 2;
  const int* esrc = eidx;
  const int* edst = eidx + E;

  // ---- workspace layout (explicit lifetime-based aliasing) ----
  char* ws = (char*)d_ws;
  // S1: x split pair (live: split_x .. gemm0)  -> then reused as h1h (gemm1 output)
  unsigned short* xh = (unsigned short*)ws_align(ws, (size_t)N * IN_CH * 2);
  unsigned short* xl = (unsigned short*)ws_align(ws, (size_t)N * IN_CH * 2);
  unsigned short* h1h = xh;  // 51.2 MB contiguous (xh+xl), written by gemm1 AFTER gemm0 read x
  // S2: z split pair (live: agg_split .. gemm1) -> then reused as h2lin (gemm2 output)
  unsigned short* zh = (unsigned short*)ws_align(ws, (size_t)N * IN_CH * 2);
  unsigned short* zl = (unsigned short*)ws_align(ws, (size_t)N * IN_CH * 2);
  float* h2lin = (float*)zh;  // 51.2 MB, written by gemm2 AFTER gemm1 read z
  // S3: h1lin fp32 (live: gemm0 .. gemm1) -> then carved into Hbf / h2h / h2l / Hb3
  float* h1lin = (float*)ws_align(ws, (size_t)N * MID * 4);
  unsigned short* Hbf = (unsigned short*)h1lin;                       // N*256*2
  unsigned short* h2h = (unsigned short*)((char*)h1lin + (size_t)N * MID2 * 2);
  unsigned short* h2l = (unsigned short*)((char*)h1lin + (size_t)N * MID2 * 4);
  float*          Hb3 = (float*)((char*)h1lin + (size_t)N * MID2 * 6);  // N*64*4
  // S4: h1l (live: gemm1 .. gemm2)
  unsigned short* h1l = (unsigned short*)ws_align(ws, (size_t)N * MID * 2);
  // persistent small stuff
  float* dis      = (float*)ws_align(ws, (size_t)N * 4);
  int*   rowstart = (int*)ws_align(ws, (size_t)(N + 1) * 4);
  int*   cnt      = (int*)ws_align(ws, (size_t)N * 4);
  int*   cnt2     = (int*)ws_align(ws, (size_t)N * 4);
  int*   adj      = (int*)ws_align(ws, (size_t)(E + N) * 4);
  // pre-split transposed weights: w1 [1024][256] (Wl1 rows 0..511, Wg1 rows 512..1023),
  // w2 [512][512] (Wl2|Wg2), w3 [128][256] (Wl3|Wg3)
  unsigned short* w1h = (unsigned short*)ws_align(ws, (size_t)1024 * IN_CH * 2);
  unsigned short* w1l = (unsigned short*)ws_align(ws, (size_t)1024 * IN_CH * 2);
  unsigned short* w2h = (unsigned short*)ws_align(ws, (size_t)512 * MID * 2);
  unsigned short* w2l = (unsigned short*)ws_align(ws, (size_t)512 * MID * 2);
  unsigned short* w3h = (unsigned short*)ws_align(ws, (size_t)128 * MID2 * 2);
  unsigned short* w3l = (unsigned short*)ws_align(ws, (size_t)128 * MID2 * 2);

  // ---- CSR build ----
  hipMemsetAsync(cnt, 0, (size_t)N * 4, stream);
  hipMemsetAsync(cnt2, 0, (size_t)N * 4, stream);
  deg_kernel<<<1024, 256, 0, stream>>>(edst, cnt, E);
  scan_dis_kernel<<<1, 1024, 0, stream>>>(cnt, rowstart, dis, N);
  fill_adj_kernel<<<2048, 256, 0, stream>>>(esrc, edst, rowstart, cnt2, adj, E, N);

  // ---- weight split (tiny) ----
  {
    int n1 = IN_CH * MID, n2 = MID * MID2, n3 = MID2 * OUT_CH;
    wsplit_cat<<<(n1 + 255) / 256, 256, 0, stream>>>(Wl1, w1h, w1l, IN_CH, MID, 0);
    wsplit_cat<<<(n1 + 255) / 256, 256, 0, stream>>>(Wg1, w1h, w1l, IN_CH, MID, MID);
    wsplit_cat<<<(n2 + 255) / 256, 256, 0, stream>>>(Wl2, w2h, w2l, MID, MID2, 0);
    wsplit_cat<<<(n2 + 255) / 256, 256, 0, stream>>>(Wg2, w2h, w2l, MID, MID2, MID2);
    wsplit_cat<<<(n3 + 255) / 256, 256, 0, stream>>>(Wl3, w3h, w3l, MID2, OUT_CH, 0);
    wsplit_cat<<<(n3 + 255) / 256, 256, 0, stream>>>(Wg3, w3h, w3l, MID2, OUT_CH, OUT_CH);
  }

  // ---- x -> bf16 split pair ----
  {
    int n8 = N * IN_CH / 8;
    split_pair<<<(n8 + 255) / 256, 256, 0, stream>>>(x, xh, xl, n8);
  }

  const int aggBlocks = (N + 3) / 4;
  const int rowBlocks = (N + 127) / 128;
  float* outp = (float*)d_out;

  // ---- layer 1 ----
  // z = agg(x) in input space (256-dim, bf16 gather on xh)
  agg_split<IN_CH><<<aggBlocks, 256, 0, stream>>>(xh, adj, rowstart, dis, zh, zl, N);
  // h1lin = x @ Wl1 + bl1
  dim3 g1(rowBlocks, MID / 128);
  gemm_ps<0><<<g1, 256, 0, stream>>>(xh, xl, w1h, w1l, bl1,
                                     nullptr, h1lin, nullptr, nullptr, nullptr,
                                     N, IN_CH, MID);
  // h1 = elu(z @ Wg1 + bg1) + h1lin  -> split pair (h1h over S1, h1l fresh)
  gemm_ps<1><<<g1, 256, 0, stream>>>(zh, zl, w1h + (size_t)MID * IN_CH, w1l + (size_t)MID * IN_CH, bg1,
                                     h1lin, nullptr, h1h, h1l, nullptr,
                                     N, IN_CH, MID);

  // ---- layer 2 ----
  // dual: h2lin = h1 @ Wl2 + bl2 ; Hbf = bf16(h1 @ Wg2)
  dim3 g2(rowBlocks, (2 * MID2) / 128);
  gemm_ps<2><<<g2, 256, 0, stream>>>(h1h, h1l, w2h, w2l, bl2,
                                     nullptr, h2lin, Hbf, nullptr, nullptr,
                                     N, MID, MID2);
  // h2 = elu(agg(Hbf)+bg2) + h2lin -> split pair
  agg_addsplit<MID2><<<aggBlocks, 256, 0, stream>>>(Hbf, adj, rowstart, dis, bg2, h2lin, h2h, h2l, N);

  // ---- layer 3 ----
  // dual: out = h2 @ Wl3 + bl3 ; Hb3 = fp32(h2 @ Wg3)
  dim3 g3(rowBlocks, (2 * OUT_CH) / 128);
  gemm_ps<3><<<g3, 256, 0, stream>>>(h2h, h2l, w3h, w3l, bl3,
                                     nullptr, outp, nullptr, nullptr, Hb3,
                                     N, MID2, OUT_CH);
  // out += agg(Hb3) + bg3
  agg_f32<OUT_CH><<<aggBlocks, 256, 0, stream>>>(Hb3, adj, rowstart, dis, bg3, outp, N);
}